// Round 1
// baseline (1375.370 us; speedup 1.0000x reference)
//
#include <hip/hip_runtime.h>
#include <stdint.h>

#define NB 8
#define NPTS 4096
#define NPOINT 1024
#define NSAMPLE 32
#define FCH 64
#define HID 128
#define CAP 320

// d2 computed with EXACT numpy rounding/order: ((dx*dx + dy*dy) + dz*dz),
// no FMA contraction (FPS argmax + radius selection must match ref bitwise).
__device__ __forceinline__ float d2_exact(float ax, float ay, float az,
                                          float bx, float by, float bz) {
  float dx = ax - bx, dy = ay - by, dz = az - bz;
  return __fadd_rn(__fadd_rn(__fmul_rn(dx, dx), __fmul_rn(dy, dy)),
                   __fmul_rn(dz, dz));
}

// ---------------------------------------------------------------- FPS
// 8 blocks (one per batch) x 512 threads. xyz in LDS, dists in regs (8/thread).
// Packed key (f32 bits << 32) | ~idx  -> max gives max-dist, ties -> min idx.
__global__ __launch_bounds__(512) void fps_kernel(const float* __restrict__ xyz,
                                                  float* __restrict__ newxyz) {
  __shared__ float xs[NPTS], ys[NPTS], zs[NPTS];
  __shared__ unsigned long long wk[2][8];
  const int b = blockIdx.x;
  const int tid = threadIdx.x;
  const float* src = xyz + (size_t)b * NPTS * 3;
  for (int j = tid; j < NPTS * 3; j += 512) {
    float v = src[j];
    int p = j / 3;
    int c = j - p * 3;
    if (c == 0) xs[p] = v;
    else if (c == 1) ys[p] = v;
    else zs[p] = v;
  }
  __syncthreads();
  float px[8], py[8], pz[8], dist[8];
  float cx = xs[0], cy = ys[0], cz = zs[0];
#pragma unroll
  for (int r = 0; r < 8; ++r) {
    int p = tid + 512 * r;
    px[r] = xs[p]; py[r] = ys[p]; pz[r] = zs[p];
    dist[r] = d2_exact(px[r], py[r], pz[r], cx, cy, cz);
  }
  if (tid == 0) {
    float* o = newxyz + (size_t)b * NPOINT * 3;
    o[0] = cx; o[1] = cy; o[2] = cz;
  }
  for (int it = 1; it < NPOINT; ++it) {
    // local argmax (strict > keeps lowest index within thread)
    float bv = dist[0];
    int bp = tid;
#pragma unroll
    for (int r = 1; r < 8; ++r)
      if (dist[r] > bv) { bv = dist[r]; bp = tid + 512 * r; }
    unsigned long long key =
        ((unsigned long long)__float_as_uint(bv) << 32) | (unsigned int)(~bp);
#pragma unroll
    for (int o = 32; o > 0; o >>= 1) {
      unsigned long long other = __shfl_xor(key, o, 64);
      if (other > key) key = other;
    }
    const int par = it & 1;
    if ((tid & 63) == 0) wk[par][tid >> 6] = key;
    __syncthreads();  // parity double-buffer -> single barrier/iter is safe
    unsigned long long gk = wk[par][0];
#pragma unroll
    for (int w = 1; w < 8; ++w) {
      unsigned long long o2 = wk[par][w];
      if (o2 > gk) gk = o2;
    }
    const int far = (int)(~(unsigned int)gk) & (NPTS - 1);
    const float ncx = xs[far], ncy = ys[far], ncz = zs[far];
    if (tid == 0) {
      float* o = newxyz + ((size_t)b * NPOINT + it) * 3;
      o[0] = ncx; o[1] = ncy; o[2] = ncz;
    }
#pragma unroll
    for (int r = 0; r < 8; ++r) {
      float d = d2_exact(px[r], py[r], pz[r], ncx, ncy, ncz);
      dist[r] = fminf(dist[r], d);
    }
  }
}

// ------------------------------------------------------------- neighbor sel
// One wave per query. Select the 32 lexicographically smallest (d2,idx) keys
// with d2 masked to +inf outside radius; the inf-fill (stable argsort) case
// == lowest-index out-of-radius points, all of which lie in the first 64 idx.
__global__ __launch_bounds__(256) void knn_kernel(const float* __restrict__ xyz,
                                                  const float* __restrict__ newxyz,
                                                  int* __restrict__ gidx) {
  __shared__ unsigned long long cand[4][CAP];
  const int wv = threadIdx.x >> 6;
  const int lane = threadIdx.x & 63;
  const int g = blockIdx.x * 4 + wv;
  const int b = g >> 10;
  const float* src = xyz + (size_t)b * NPTS * 3;
  const float cx = newxyz[g * 3 + 0];
  const float cy = newxyz[g * 3 + 1];
  const float cz = newxyz[g * 3 + 2];
  const float r2 = 0.0225f;  // np float32(RADIUS**2)
  int cnt = 0;
  for (int j0 = 0; j0 < NPTS; j0 += 64) {
    const int p = j0 + lane;
    const float* pp = src + p * 3;
    float d2 = d2_exact(pp[0], pp[1], pp[2], cx, cy, cz);
    bool inr = (d2 <= r2);
    unsigned long long mask = __ballot(inr);
    if (inr) {
      int pos = cnt + __popcll(mask & ((1ull << lane) - 1ull));
      if (pos < CAP)
        cand[wv][pos] =
            ((unsigned long long)__float_as_uint(d2) << 32) | (unsigned int)p;
    }
    cnt += __popcll(mask);
  }
  int C = cnt < CAP ? cnt : CAP;
  int* out = gidx + g * NSAMPLE;
  // rank selection: keys distinct -> ranks unique; rank<32 selected
  for (int t = lane; t < C; t += 64) {
    unsigned long long kt = cand[wv][t];
    int rank = 0;
    for (int u = 0; u < C; ++u) rank += (cand[wv][u] < kt) ? 1 : 0;
    if (rank < NSAMPLE) out[rank] = (int)(kt & 0xffffffffu);
  }
  if (C < NSAMPLE) {  // boundary query: fill with lowest-index outside-radius
    const float* pp = src + lane * 3;
    float d2 = d2_exact(pp[0], pp[1], pp[2], cx, cy, cz);
    bool outr = !(d2 <= r2);
    unsigned long long mask = __ballot(outr);
    if (outr) {
      int pos = __popcll(mask & ((1ull << lane) - 1ull));
      if (pos < NSAMPLE - C) out[C + pos] = lane;
    }
  }
}

// ---------------------------------------------------------------- MLP
// One block (256 thr) per query. Thread tile = 4 samples x 4 channels.
// K-vectorized float4 LDS activation reads; weights streamed from L2.
template <int K>
__device__ __forceinline__ void gemm_tile(const float* __restrict__ a0,
                                          const float* __restrict__ a1,
                                          const float* __restrict__ a2,
                                          const float* __restrict__ a3,
                                          const float* __restrict__ W,
                                          const float* __restrict__ bias,
                                          int c0, float acc[4][4]) {
  float4 bv = *(const float4*)(bias + c0);
#pragma unroll
  for (int i = 0; i < 4; ++i) {
    acc[i][0] = bv.x; acc[i][1] = bv.y; acc[i][2] = bv.z; acc[i][3] = bv.w;
  }
  int k = 0;
  for (; k + 4 <= K; k += 4) {
    float4 A0 = *(const float4*)(a0 + k);
    float4 A1 = *(const float4*)(a1 + k);
    float4 A2 = *(const float4*)(a2 + k);
    float4 A3 = *(const float4*)(a3 + k);
#pragma unroll
    for (int kk = 0; kk < 4; ++kk) {
      float4 w = *(const float4*)(W + (size_t)(k + kk) * HID + c0);
      float e0 = (&A0.x)[kk], e1 = (&A1.x)[kk], e2 = (&A2.x)[kk], e3 = (&A3.x)[kk];
      acc[0][0] += e0 * w.x; acc[0][1] += e0 * w.y; acc[0][2] += e0 * w.z; acc[0][3] += e0 * w.w;
      acc[1][0] += e1 * w.x; acc[1][1] += e1 * w.y; acc[1][2] += e1 * w.z; acc[1][3] += e1 * w.w;
      acc[2][0] += e2 * w.x; acc[2][1] += e2 * w.y; acc[2][2] += e2 * w.z; acc[2][3] += e2 * w.w;
      acc[3][0] += e3 * w.x; acc[3][1] += e3 * w.y; acc[3][2] += e3 * w.z; acc[3][3] += e3 * w.w;
    }
  }
  for (; k < K; ++k) {
    float4 w = *(const float4*)(W + (size_t)k * HID + c0);
    float e0 = a0[k], e1 = a1[k], e2 = a2[k], e3 = a3[k];
    acc[0][0] += e0 * w.x; acc[0][1] += e0 * w.y; acc[0][2] += e0 * w.z; acc[0][3] += e0 * w.w;
    acc[1][0] += e1 * w.x; acc[1][1] += e1 * w.y; acc[1][2] += e1 * w.z; acc[1][3] += e1 * w.w;
    acc[2][0] += e2 * w.x; acc[2][1] += e2 * w.y; acc[2][2] += e2 * w.z; acc[2][3] += e2 * w.w;
    acc[3][0] += e3 * w.x; acc[3][1] += e3 * w.y; acc[3][2] += e3 * w.z; acc[3][3] += e3 * w.w;
  }
}

__global__ __launch_bounds__(256) void mlp_kernel(
    const float* __restrict__ xyz, const float* __restrict__ feats,
    const float* __restrict__ W1f, const float* __restrict__ b1f,
    const float* __restrict__ W2f, const float* __restrict__ b2f,
    const float* __restrict__ W1w, const float* __restrict__ b1w,
    const float* __restrict__ W2w, const float* __restrict__ b2w,
    const int* __restrict__ gidx, const float* __restrict__ newxyz,
    float* __restrict__ fout) {
  __shared__ float fin[32][72];    // [s][0..2]=dxyz, [3..66]=feats
  __shared__ float buf1[32][132];  // h1 (128) then w_in (131)
  __shared__ float fp[32][HID];    // f_prime
  __shared__ float h2[32][HID];
  __shared__ float fm[HID];
  __shared__ float red[8][HID];
  __shared__ int sidx[32];

  const int g = blockIdx.x;
  const int b = g >> 10;
  const int t = threadIdx.x;

  if (t < 32) sidx[t] = gidx[g * NSAMPLE + t];
  const float cx = newxyz[g * 3 + 0];
  const float cy = newxyz[g * 3 + 1];
  const float cz = newxyz[g * 3 + 2];
  __syncthreads();
  if (t < 32) {
    const float* pp = xyz + ((size_t)b * NPTS + sidx[t]) * 3;
    fin[t][0] = pp[0] - cx;
    fin[t][1] = pp[1] - cy;
    fin[t][2] = pp[2] - cz;
  }
  for (int e = t; e < 32 * FCH; e += 256) {
    int s = e >> 6;
    int c = e & 63;
    fin[s][3 + c] = feats[((size_t)b * NPTS + sidx[s]) * FCH + c];
  }
  __syncthreads();

  const int s0 = (t >> 5) * 4;
  const int c0 = (t & 31) * 4;
  float acc[4][4];

  // G1: relu(f_in @ W1f + b1f) -> buf1
  gemm_tile<67>(fin[s0], fin[s0 + 1], fin[s0 + 2], fin[s0 + 3], W1f, b1f, c0, acc);
#pragma unroll
  for (int i = 0; i < 4; ++i)
#pragma unroll
    for (int j = 0; j < 4; ++j) buf1[s0 + i][c0 + j] = fmaxf(acc[i][j], 0.f);
  __syncthreads();

  // G2: relu(h1 @ W2f + b2f) -> fp
  gemm_tile<128>(buf1[s0], buf1[s0 + 1], buf1[s0 + 2], buf1[s0 + 3], W2f, b2f, c0, acc);
#pragma unroll
  for (int i = 0; i < 4; ++i)
#pragma unroll
    for (int j = 0; j < 4; ++j) fp[s0 + i][c0 + j] = fmaxf(acc[i][j], 0.f);
  __syncthreads();

  // mean over samples
  if (t < HID) {
    float s = 0.f;
#pragma unroll 8
    for (int i = 0; i < 32; ++i) s += fp[i][t];
    fm[t] = s * (1.0f / 32.0f);
  }
  __syncthreads();

  // w_in = [dxyz, fp - fm] -> buf1 (131 cols)
  for (int e = t; e < 32 * 131; e += 256) {
    int s = e / 131;
    int c = e - s * 131;
    buf1[s][c] = (c < 3) ? fin[s][c] : (fp[s][c - 3] - fm[c - 3]);
  }
  __syncthreads();

  // G3: relu(w_in @ W1w + b1w) -> h2
  gemm_tile<131>(buf1[s0], buf1[s0 + 1], buf1[s0 + 2], buf1[s0 + 3], W1w, b1w, c0, acc);
#pragma unroll
  for (int i = 0; i < 4; ++i)
#pragma unroll
    for (int j = 0; j < 4; ++j) h2[s0 + i][c0 + j] = fmaxf(acc[i][j], 0.f);
  __syncthreads();

  // G4: alpha = sigmoid(h2 @ W2w + b2w); partial f_out = sum_s alpha*fp
  gemm_tile<128>(h2[s0], h2[s0 + 1], h2[s0 + 2], h2[s0 + 3], W2w, b2w, c0, acc);
  {
    float part[4] = {0.f, 0.f, 0.f, 0.f};
#pragma unroll
    for (int i = 0; i < 4; ++i)
#pragma unroll
      for (int j = 0; j < 4; ++j) {
        float al = 1.0f / (1.0f + __expf(-acc[i][j]));
        part[j] += al * fp[s0 + i][c0 + j];
      }
    red[t >> 5][c0 + 0] = part[0];
    red[t >> 5][c0 + 1] = part[1];
    red[t >> 5][c0 + 2] = part[2];
    red[t >> 5][c0 + 3] = part[3];
  }
  __syncthreads();
  if (t < HID) {
    float s = 0.f;
#pragma unroll
    for (int w = 0; w < 8; ++w) s += red[w][t];
    fout[(size_t)g * HID + t] = s;
  }
}

extern "C" void kernel_launch(void* const* d_in, const int* in_sizes, int n_in,
                              void* d_out, int out_size, void* d_ws, size_t ws_size,
                              hipStream_t stream) {
  const float* xyz = (const float*)d_in[0];
  const float* feats = (const float*)d_in[1];
  const float* W1f = (const float*)d_in[2];
  const float* b1f = (const float*)d_in[3];
  const float* W2f = (const float*)d_in[4];
  const float* b2f = (const float*)d_in[5];
  const float* W1w = (const float*)d_in[6];
  const float* b1w = (const float*)d_in[7];
  const float* W2w = (const float*)d_in[8];
  const float* b2w = (const float*)d_in[9];

  float* newxyz = (float*)d_out;                          // (8,1024,3)
  float* fout = (float*)d_out + (size_t)NB * NPOINT * 3;  // (8,1024,128)
  int* gidx = (int*)d_ws;                                 // (8192,32)

  fps_kernel<<<NB, 512, 0, stream>>>(xyz, newxyz);
  knn_kernel<<<NB * NPOINT / 4, 256, 0, stream>>>(xyz, newxyz, gidx);
  mlp_kernel<<<NB * NPOINT, 256, 0, stream>>>(xyz, feats, W1f, b1f, W2f, b2f,
                                              W1w, b1w, W2w, b2w, gidx, newxyz,
                                              fout);
}